// Round 9
// baseline (3552.404 us; speedup 1.0000x reference)
//
#include <hip/hip_runtime.h>
#include <hip/hip_bf16.h>

#define DT 0.1f
#define TAU_HP 12.3f
#define TAU_LP 2.3f
#define SCAN_B 1024
#define CHUNK 32768        // edges per block in hist/bin passes (64K regressed: R10)

// R11 tiling: block owns RB target rows; sources tiled SR per LDS pass.
#define RB 512
#define RBBITS 9
#define SR 16384
#define SRBITS 14
#define BKMAX 5120         // >= ceil(n/RB)*ceil(n/SR) = 391*13 = 5083

// ---------------------------------------------------------------------------
// R5:  8 lanes/row remap. NEUTRAL -> not wave-slot-bound.
// R6:  cooperative all-steps kernel. 9457us (5x WORSE). REVERTED.
// R7:  relu-mask w/ global reads. 2179us: mask load was itself VMEM.
// R8:  mask in LDS. 1779us WIN. Gather predication saved ~0 -> step bound by
//      per-lane random VMEM request processing (~3cy/line-req matches 28us).
// R9:  direct-scatter build. 2123us (346MB writes). REVERTED.
// R10: CHUNK 64K. 1828us: bin 135->165us, occupancy 30->15% (98 blocks
//      underfills 256 CUs). REVERTED to 32K.
// R11: STRUCTURAL: source-tiled LDS gather. Eliminates ALL random VMEM:
//      block = 512 rows; for each of 13 source-ranges: stage relu(vr) tile
//      (64KB, coalesced) -> edges of that (block,range) segment do
//      ds_read(tile) + ds_add(acc). Radix key -> (tgt>>9)*NR + (src>>14);
//      finalize/row_start/mask machinery deleted (relu folded into staging).
//      Tm1 blocks have empty segments; filters unchanged.
// ---------------------------------------------------------------------------

__global__ void init_kernel(float* __restrict__ vA,
                            float* __restrict__ tm1_f,
                            int n_neurons, int n_tm1) {
    int i = blockIdx.x * blockDim.x + threadIdx.x;
    if (i < n_neurons) vA[i] = 0.0f;
    if (i < n_tm1) tm1_f[i] = 0.0f;
}

// --- build pass 1: per-(chunk,bucket) histogram; key = rowblk*NR + srcrange --
__global__ void bhist_kernel(const int* __restrict__ src,
                             const int* __restrict__ tgt,
                             int* __restrict__ blkhist,
                             int n_edges, int n_tm1, int nbkt, int NR, int nblk) {
    __shared__ int hist[BKMAX];
    int b = blockIdx.x;
    for (int i = threadIdx.x; i < nbkt; i += blockDim.x) hist[i] = 0;
    __syncthreads();
    int base = b * CHUNK;
    int end = min(base + CHUNK, n_edges);
    for (int k = base + threadIdx.x; k < end; k += blockDim.x) {
        int t = tgt[k];
        if (t >= n_tm1)
            atomicAdd(&hist[(t >> RBBITS) * NR + (src[k] >> SRBITS)], 1);
    }
    __syncthreads();
    for (int i = threadIdx.x; i < nbkt; i += blockDim.x)
        blkhist[(size_t)i * nblk + b] = hist[i];      // bucket-major for scan
}

// --- 3-level exclusive scan --------------------------------------------------
__global__ void scan1_kernel(const int* in, int* out, int* bsums, int n) {
    __shared__ int s[SCAN_B];
    int gid = blockIdx.x * SCAN_B + threadIdx.x;
    int x = (gid < n) ? in[gid] : 0;
    s[threadIdx.x] = x;
    __syncthreads();
    for (int off = 1; off < SCAN_B; off <<= 1) {
        int t = (threadIdx.x >= off) ? s[threadIdx.x - off] : 0;
        __syncthreads();
        s[threadIdx.x] += t;
        __syncthreads();
    }
    if (gid < n) out[gid] = s[threadIdx.x] - x;       // exclusive
    if (threadIdx.x == SCAN_B - 1) bsums[blockIdx.x] = s[SCAN_B - 1];
}

__global__ void scan2_kernel(int* bsums, int nb, int* total) {
    __shared__ int s[SCAN_B];
    int x = (threadIdx.x < nb) ? bsums[threadIdx.x] : 0;
    s[threadIdx.x] = x;
    __syncthreads();
    for (int off = 1; off < SCAN_B; off <<= 1) {
        int t = (threadIdx.x >= off) ? s[threadIdx.x - off] : 0;
        __syncthreads();
        s[threadIdx.x] += t;
        __syncthreads();
    }
    if (threadIdx.x == nb - 1) *total = s[threadIdx.x];   // inclusive grand total
    if (threadIdx.x < nb) bsums[threadIdx.x] = s[threadIdx.x] - x;
}

__global__ void scanadd_kernel(int* data, const int* __restrict__ bsums, int n) {
    int gid = blockIdx.x * blockDim.x + threadIdx.x;
    if (gid < n) data[gid] += bsums[gid / SCAN_B];
}

// --- build pass 2: bin kept edges into (rowblk,srcrange) segments ------------
// record = (src_local | tgt_local<<SRBITS, weight-bits): 14+9 bits + f32.
__global__ void bin_kernel(const int* __restrict__ src, const int* __restrict__ tgt,
                           const float* __restrict__ w, const int* __restrict__ scanned,
                           int2* __restrict__ edges, int n_edges, int n_tm1,
                           int nbkt, int NR, int nblk) {
    __shared__ int cur[BKMAX];
    int b = blockIdx.x;
    for (int i = threadIdx.x; i < nbkt; i += blockDim.x)
        cur[i] = scanned[(size_t)i * nblk + b];
    __syncthreads();
    int base = b * CHUNK;
    int end = min(base + CHUNK, n_edges);
    for (int k = base + threadIdx.x; k < end; k += blockDim.x) {
        int t = tgt[k];
        if (t < n_tm1) continue;                      // dead edges (dv[:tm1]=0)
        int s = src[k];
        int key = (t >> RBBITS) * NR + (s >> SRBITS);
        int pos = atomicAdd(&cur[key], 1);            // LDS atomic
        edges[pos] = make_int2((s & (SR - 1)) | ((t & (RB - 1)) << SRBITS),
                               __float_as_int(w[k]));
    }
}

// --- compact segment table: seg[i] = start of bucket i -----------------------
__global__ void mkseg_kernel(const int* __restrict__ scanned, int* __restrict__ seg,
                             const int* __restrict__ total, int nbkt, int nblk) {
    int i = blockIdx.x * blockDim.x + threadIdx.x;
    if (i < nbkt) seg[i] = scanned[(size_t)i * nblk];
    if (i == nbkt) seg[nbkt] = *total;
}

// --- fused per-step kernel: source-tiled LDS gather --------------------------
// Block b owns rows [b*RB, b*RB+RB). For each source range r with edges:
// stage relu(vr[range]) -> tile (coalesced), then segment edges do
// ds_read(tile) * w -> ds_add(acc). Zero random VMEM. Tm1 rows: filters.
__global__ __launch_bounds__(1024)
void step2_kernel(const int* __restrict__ seg,
                  const int2* __restrict__ edges,
                  const float* __restrict__ vr,
                  float* __restrict__ vw,
                  float* __restrict__ tm1_f,
                  const float* __restrict__ x,     // tm1_input + k*n_tm1
                  const float* __restrict__ tau,
                  const float* __restrict__ vrest,
                  int n_neurons, int n_tm1, int NR, int last) {
    __shared__ float tile[SR];
    __shared__ float acc[RB];
    int tid = threadIdx.x;
    int b = blockIdx.x;
    int rowbase = b << RBBITS;
    if (tid < RB) acc[tid] = 0.0f;

    int segbase = b * NR;
    int e_first = seg[segbase];
    int e_last  = seg[segbase + NR];

    if (e_last > e_first) {                   // block-uniform
        for (int r = 0; r < NR; ++r) {
            int e0 = seg[segbase + r], e1 = seg[segbase + r + 1];
            if (e1 == e0) continue;           // block-uniform
            int sbase = r << SRBITS;
            if (sbase + SR <= n_neurons) {    // fast path: full range, float4
                const float4* v4 = (const float4*)(vr + sbase);
                float4* t4 = (float4*)tile;
                for (int i = tid; i < SR / 4; i += 1024) {
                    float4 v = v4[i];
                    v.x = fmaxf(v.x, 0.0f); v.y = fmaxf(v.y, 0.0f);
                    v.z = fmaxf(v.z, 0.0f); v.w = fmaxf(v.w, 0.0f);
                    t4[i] = v;
                }
            } else {                          // tail range: clamp
                for (int i = tid; i < SR; i += 1024) {
                    int g = sbase + i;
                    tile[i] = (g < n_neurons) ? fmaxf(vr[g], 0.0f) : 0.0f;
                }
            }
            __syncthreads();
            for (int e = e0 + tid; e < e1; e += 1024) {
                int2 rec = edges[e];
                atomicAdd(&acc[rec.x >> SRBITS],
                          tile[rec.x & (SR - 1)] * __int_as_float(rec.y));
            }
            __syncthreads();                  // drain atomics / protect tile
        }
    }

    if (tid < RB) {
        int row = rowbase + tid;
        if (row < n_neurons) {
            if (row < n_tm1) {                // Tm1 row: filter update only
                float cur = vr[row];          // = tm1_v at step k
                if (last) {
                    vw[row] = cur;            // ref: v[:tm1] = old tm1_v
                } else {
                    float f  = tm1_f[row];
                    float xk = x[row];
                    float hp = xk - f;
                    tm1_f[row] = f + DT * (xk - f) / TAU_HP;
                    vw[row] = cur + DT * (fmaxf(hp, 0.0f) - cur) / TAU_LP;
                }
            } else {
                float vi = vr[row];
                vw[row] = vi + DT * ((-vi + acc[tid] + vrest[row]) / tau[row]);
            }
        }
    }
}

extern "C" void kernel_launch(void* const* d_in, const int* in_sizes, int n_in,
                              void* d_out, int out_size, void* d_ws, size_t ws_size,
                              hipStream_t stream) {
    const float* tm1_input  = (const float*)d_in[0];
    const float* weights    = (const float*)d_in[1];
    const float* tau        = (const float*)d_in[2];
    const float* vrest      = (const float*)d_in[3];
    const int*   source_idx = (const int*)d_in[4];
    const int*   target_idx = (const int*)d_in[5];

    const int n_edges   = in_sizes[1];
    const int n_neurons = in_sizes[2];
    const int n_tm1     = 25000;
    const int steps     = in_sizes[0] / n_tm1;

    const int NR     = (n_neurons + SR - 1) / SR;            // 13
    const int nbRows = (n_neurons + RB - 1) / RB;            // 391
    const int nbkt   = nbRows * NR;                          // 5083 <= BKMAX
    const int nblk   = (n_edges + CHUNK - 1) / CHUNK;        // 196
    const int n_scan = nbkt * nblk;                          // 996,268 <= 1024^2

    // Workspace (4-byte units). edges first -> 16B aligned.
    size_t off = 0;
    auto alloc = [&](size_t n) { size_t o = off; off += n; return o; };
    int* ws_i = (int*)d_ws;
    float* ws_f = (float*)d_ws;

    int2*  edges   = (int2*)(ws_i + alloc((size_t)(n_edges + 2) * 2));
    float* vA      = ws_f + alloc(n_neurons);
    float* vB      = ws_f + alloc(n_neurons);
    float* tm1_f   = ws_f + alloc(n_tm1);
    int*   seg     = ws_i + alloc(nbkt + 1);
    int*   blkhist = ws_i + alloc((size_t)n_scan);
    int*   bsums   = ws_i + alloc(SCAN_B);
    int*   total   = ws_i + alloc(1);
    (void)ws_size;

    float* out = (float*)d_out;

    const int B = 256;
    const int gridN = (n_neurons + B - 1) / B;
    const int nScanBlocks = (n_scan + SCAN_B - 1) / SCAN_B;  // 973 <= 1024
    const int gridSA = (n_scan + B - 1) / B;
    const int gridSeg = (nbkt + 1 + B - 1) / B;

    // --- one-time (per launch) CSR build: zero global atomics ---
    init_kernel<<<gridN, B, 0, stream>>>(vA, tm1_f, n_neurons, n_tm1);
    bhist_kernel<<<nblk, 1024, 0, stream>>>(source_idx, target_idx, blkhist,
                                            n_edges, n_tm1, nbkt, NR, nblk);
    scan1_kernel<<<nScanBlocks, SCAN_B, 0, stream>>>(blkhist, blkhist, bsums, n_scan);
    scan2_kernel<<<1, SCAN_B, 0, stream>>>(bsums, nScanBlocks, total);
    scanadd_kernel<<<gridSA, B, 0, stream>>>(blkhist, bsums, n_scan);
    bin_kernel<<<nblk, 1024, 0, stream>>>(source_idx, target_idx, weights, blkhist,
                                          edges, n_edges, n_tm1, nbkt, NR, nblk);
    mkseg_kernel<<<gridSeg, B, 0, stream>>>(blkhist, seg, total, nbkt, nblk);

    // --- steps: ONE tiled kernel per step, double-buffered v ---
    for (int k = 0; k < steps; ++k) {
        const float* vr = (k & 1) ? vB : vA;
        float* vw = (k == steps - 1) ? out : ((k & 1) ? vA : vB);
        step2_kernel<<<nbRows, 1024, 0, stream>>>(
            seg, edges, vr, vw, tm1_f,
            tm1_input + (size_t)k * n_tm1,
            tau, vrest, n_neurons, n_tm1, NR, (k == steps - 1) ? 1 : 0);
    }
}